// Round 2
// baseline (358.899 us; speedup 1.0000x reference)
//
#include <hip/hip_runtime.h>
#include <hip/hip_bf16.h>
#include <hip/hip_cooperative_groups.h>

namespace cg = cooperative_groups;

#define N_NODES 50000
#define N_EDGES 800000
#define LATDIM 128
#define HEAD 4
#define SLOT_CAP 96

#define BLOCK_T 768
#define SCAT_UNITS ((N_EDGES / 4 + BLOCK_T - 1) / BLOCK_T)    // 261
#define GEMM_TILES ((N_NODES + 63) / 64)                       // 782
#define FUSE_WAVES 12
#define FUSE_GROUPS ((N_NODES + FUSE_WAVES - 1) / FUSE_WAVES)  // 4167
#define LDSP 136   // shorts per LDS row (128 + 8 pad)

typedef __attribute__((ext_vector_type(8))) short short8;
typedef __attribute__((ext_vector_type(4))) float floatx4;

// ---------------------------------------------------------------------------
// fp32 -> bf16 helpers (RNE via bit math; inputs are finite)
// ---------------------------------------------------------------------------
__device__ __forceinline__ unsigned bf16_rne_bits(float x) {
    unsigned u = __builtin_bit_cast(unsigned, x);
    return (u + 0x7fffu + ((u >> 16) & 1u)) & 0xffff0000u;
}
__device__ __forceinline__ void split_bf16(float x, short& hi, short& lo) {
    unsigned hb = bf16_rne_bits(x);
    hi = (short)(hb >> 16);
    float hf = __builtin_bit_cast(float, hb);
    unsigned lb = bf16_rne_bits(x - hf);
    lo = (short)(lb >> 16);
}

// ---------------------------------------------------------------------------
// slotted edge scatter: slots[r*96 + p] = c, p from per-node atomic bump
// ---------------------------------------------------------------------------
__device__ __forceinline__ void scatter_unit(
    int u, const int* __restrict__ rows, const int* __restrict__ cols,
    int* __restrict__ cnt, int* __restrict__ slots, int tid)
{
    const int t = u * BLOCK_T + tid;
    if (t < N_EDGES / 4) {
        int4 r = ((const int4*)rows)[t];
        int4 c = ((const int4*)cols)[t];
        int p;
        p = atomicAdd(&cnt[r.x], 1);
        if (p < SLOT_CAP) slots[(size_t)r.x * SLOT_CAP + p] = c.x;
        p = atomicAdd(&cnt[r.y], 1);
        if (p < SLOT_CAP) slots[(size_t)r.y * SLOT_CAP + p] = c.y;
        p = atomicAdd(&cnt[r.z], 1);
        if (p < SLOT_CAP) slots[(size_t)r.z * SLOT_CAP + p] = c.z;
        p = atomicAdd(&cnt[r.w], 1);
        if (p < SLOT_CAP) slots[(size_t)r.w * SLOT_CAP + p] = c.w;
    }
}

// ---------------------------------------------------------------------------
// Persistent cooperative kernel. One grid sized to resident capacity.
//   Phase 1a: each block grabs <=1 scatter unit (ticket tk[0]) -> overlaps
//             with phase 1b on other blocks.
//   Phase 1b: gemm tiles via ticket tk[1]. 12 waves = 3 projections x 4
//             col-stripes share a 64-row A-tile staged in LDS (fp32 embeds
//             hi/lo-split inline). B frags read straight from fp32 W.
//   Phase 1c: leftover scatter units (only if grid < SCAT_UNITS).
//   grid.sync()
//   Phase 2:  fused attention, 12 nodes/block per ticket tk[2].
// Output layout unchanged: Q fp32 [N][128]; KV2[n][h*64 + {0..31:K, 32..63:V}].
// Ticket broadcast discipline: write s_g -> sync -> read -> sync. The second
// sync makes the read safe against the NEXT write (writer must pass it too).
// ---------------------------------------------------------------------------
__global__ __launch_bounds__(BLOCK_T) void persist_kernel(
    const float* __restrict__ E,
    const float* __restrict__ qW, const float* __restrict__ kW,
    const float* __restrict__ vW,
    const int* __restrict__ rows, const int* __restrict__ cols,
    int* __restrict__ cnt, int* __restrict__ slots, int* __restrict__ tk,
    float* __restrict__ Q, unsigned short* __restrict__ KV2,
    float* __restrict__ out)
{
    __shared__ short AhL[64 * LDSP];
    __shared__ short AlL[64 * LDSP];
    __shared__ int s_g;

    const int tid  = threadIdx.x;
    const int wave = tid >> 6;
    const int lane = tid & 63;

    // ---- phase 1a: one scatter unit per block ----
    if (tid == 0) s_g = atomicAdd(&tk[0], 1);
    __syncthreads();
    {
        const int su = s_g;
        __syncthreads();
        if (su < SCAT_UNITS) scatter_unit(su, rows, cols, cnt, slots, tid);
    }

    // ---- B fragments (per wave role, loaded once; W is L2-resident) ----
    const int which  = wave >> 2;            // 0=Q, 1=K, 2=V
    const int n_base = (wave & 3) * 32;
    const int ln = lane & 15;
    const int q  = lane >> 4;
    const float* W = (which == 0) ? qW : (which == 1) ? kW : vW;
    short8 Bh[2][4], Bl[2][4];
#pragma unroll
    for (int tIdx = 0; tIdx < 2; ++tIdx)
#pragma unroll
        for (int c = 0; c < 4; ++c)
#pragma unroll
            for (int j = 0; j < 8; ++j) {
                float w = W[(c * 32 + q * 8 + j) * 128 + n_base + tIdx * 16 + ln];
                short hi, lo;
                split_bf16(w, hi, lo);
                Bh[tIdx][c][j] = hi;
                Bl[tIdx][c][j] = lo;
            }

    const int vs = (which == 2) ? 32 : 0;
    const int c0 = n_base + ln;
    const int c1 = n_base + 16 + ln;

    // ---- phase 1b: gemm tiles via ticket ----
    for (;;) {
        if (tid == 0) s_g = atomicAdd(&tk[1], 1);
        __syncthreads();                  // all waves done with prior LDS reads
        const int tile = s_g;
        __syncthreads();
        if (tile >= GEMM_TILES) break;

        const int r_base = tile * 64;
        // stage + convert: 64 rows x 32 float4 = 2048 chunks
        for (int chnk = tid; chnk < 2048; chnk += BLOCK_T) {
            const int row = chnk >> 5, c4 = chnk & 31;
            int grow = r_base + row;
            if (grow > N_NODES - 1) grow = N_NODES - 1;
            float4 x = ((const float4*)E)[(size_t)grow * 32 + c4];
            short h0, l0, h1, l1, h2, l2, h3, l3;
            split_bf16(x.x, h0, l0);
            split_bf16(x.y, h1, l1);
            split_bf16(x.z, h2, l2);
            split_bf16(x.w, h3, l3);
            *(short4*)(AhL + row * LDSP + c4 * 4) = make_short4(h0, h1, h2, h3);
            *(short4*)(AlL + row * LDSP + c4 * 4) = make_short4(l0, l1, l2, l3);
        }
        __syncthreads();

        for (int rt = 0; rt < 4; ++rt) {
            const short* ah = AhL + (rt * 16 + ln) * LDSP + q * 8;
            const short* al = AlL + (rt * 16 + ln) * LDSP + q * 8;

            floatx4 acc0 = {0.f, 0.f, 0.f, 0.f};
            floatx4 acc1 = {0.f, 0.f, 0.f, 0.f};
#pragma unroll
            for (int c = 0; c < 4; ++c) {
                short8 Ah = *(const short8*)(ah + c * 32);
                short8 Al = *(const short8*)(al + c * 32);
                acc0 = __builtin_amdgcn_mfma_f32_16x16x32_bf16(Ah, Bh[0][c], acc0, 0, 0, 0);
                acc0 = __builtin_amdgcn_mfma_f32_16x16x32_bf16(Ah, Bl[0][c], acc0, 0, 0, 0);
                acc0 = __builtin_amdgcn_mfma_f32_16x16x32_bf16(Al, Bh[0][c], acc0, 0, 0, 0);
                acc1 = __builtin_amdgcn_mfma_f32_16x16x32_bf16(Ah, Bh[1][c], acc1, 0, 0, 0);
                acc1 = __builtin_amdgcn_mfma_f32_16x16x32_bf16(Ah, Bl[1][c], acc1, 0, 0, 0);
                acc1 = __builtin_amdgcn_mfma_f32_16x16x32_bf16(Al, Bh[1][c], acc1, 0, 0, 0);
            }

            const int r0 = r_base + rt * 16;
#pragma unroll
            for (int r = 0; r < 4; ++r) {
                const int row = r0 + q * 4 + r;
                if (row >= N_NODES) continue;
                if (which == 0) {
                    Q[(size_t)row * 128 + c0] = acc0[r];
                    Q[(size_t)row * 128 + c1] = acc1[r];
                } else {
                    KV2[(size_t)row * 256 + (c0 >> 5) * 64 + (c0 & 31) + vs] =
                        (unsigned short)(bf16_rne_bits(acc0[r]) >> 16);
                    KV2[(size_t)row * 256 + (c1 >> 5) * 64 + (c1 & 31) + vs] =
                        (unsigned short)(bf16_rne_bits(acc1[r]) >> 16);
                }
            }
        }
    }

    // ---- phase 1c: leftover scatter units (no-op when grid >= SCAT_UNITS) ----
    for (;;) {
        if (tid == 0) s_g = atomicAdd(&tk[0], 1);
        __syncthreads();
        const int u = s_g;
        __syncthreads();
        if (u >= SCAT_UNITS) break;
        scatter_unit(u, rows, cols, cnt, slots, tid);
    }

    // ---- grid-wide barrier: Q/KV2/cnt/slots complete ----
    __threadfence();
    cg::this_grid().sync();

    // ---- phase 2: fused attention, 12 nodes per ticket ----
    const int s  = lane & 1;
    const int h  = (lane >> 1) & 3;
    const int el = lane >> 3;

    for (;;) {
        if (tid == 0) s_g = atomicAdd(&tk[2], 1);
        __syncthreads();
        const int g = s_g;
        __syncthreads();
        if (g >= FUSE_GROUPS) break;
        const int n = g * FUSE_WAVES + wave;
        if (n < N_NODES) {
            int deg = cnt[n];
            if (deg > SLOT_CAP) deg = SLOT_CAP;

            float qv[16];
            {
                const float4* qp = (const float4*)(Q + (size_t)n * 128 + h * 32 + s * 16);
#pragma unroll
                for (int j = 0; j < 4; ++j) {
                    float4 t = qp[j];
                    qv[4 * j + 0] = t.x; qv[4 * j + 1] = t.y;
                    qv[4 * j + 2] = t.z; qv[4 * j + 3] = t.w;
                }
            }

            float acc[16];
#pragma unroll
            for (int j = 0; j < 16; ++j) acc[j] = 0.f;
            float norm = 0.f;

            const int* srow = slots + (size_t)n * SLOT_CAP;

            for (int i = 0; i < deg; i += 8) {
                const int e = i + el;
                if (e < deg) {
                    const int col = srow[e];
                    const unsigned short* kp = KV2 + (size_t)col * 256 + h * 64 + s * 16;
                    uint4 k0 = *(const uint4*)(kp);
                    uint4 k1 = *(const uint4*)(kp + 8);
                    uint4 v0 = *(const uint4*)(kp + 32);
                    uint4 v1 = *(const uint4*)(kp + 40);

                    unsigned kw[8] = {k0.x, k0.y, k0.z, k0.w, k1.x, k1.y, k1.z, k1.w};
                    float p = 0.f;
#pragma unroll
                    for (int d = 0; d < 8; ++d) {
                        float flo = __builtin_bit_cast(float, kw[d] << 16);
                        float fhi = __builtin_bit_cast(float, kw[d] & 0xffff0000u);
                        p += qv[2 * d] * flo + qv[2 * d + 1] * fhi;
                    }
                    p += __shfl_xor(p, 1);   // combine the two halves of this head

                    float a = expf(fminf(fmaxf(p, -10.0f), 10.0f));
                    norm += a;

                    unsigned vw[8] = {v0.x, v0.y, v0.z, v0.w, v1.x, v1.y, v1.z, v1.w};
#pragma unroll
                    for (int d = 0; d < 8; ++d) {
                        float flo = __builtin_bit_cast(float, vw[d] << 16);
                        float fhi = __builtin_bit_cast(float, vw[d] & 0xffff0000u);
                        acc[2 * d]     += a * flo;
                        acc[2 * d + 1] += a * fhi;
                    }
                }
            }

            // reduce over the 8 edge-slot lanes
#pragma unroll
            for (int m = 8; m <= 32; m <<= 1) {
                norm += __shfl_xor(norm, m, 64);
#pragma unroll
                for (int j = 0; j < 16; ++j) acc[j] += __shfl_xor(acc[j], m, 64);
            }

            if (el == 0) {
                const float inv = 1.0f / (norm + 1e-8f);
                float4* op = (float4*)(out + (size_t)n * 128 + h * 32 + s * 16);
#pragma unroll
                for (int j = 0; j < 4; ++j)
                    op[j] = make_float4(acc[4 * j] * inv, acc[4 * j + 1] * inv,
                                        acc[4 * j + 2] * inv, acc[4 * j + 3] * inv);
            }
        }
        // no trailing sync needed: s_g re-write is fenced by the double sync
    }
}

// ---------------------------------------------------------------------------
extern "C" void kernel_launch(void* const* d_in, const int* in_sizes, int n_in,
                              void* d_out, int out_size, void* d_ws, size_t ws_size,
                              hipStream_t stream) {
    const float* embeds = (const float*)d_in[0];
    const float* qW     = (const float*)d_in[1];
    const float* kW     = (const float*)d_in[2];
    const float* vW     = (const float*)d_in[3];
    const int*   rows   = (const int*)d_in[4];
    const int*   cols   = (const int*)d_in[5];
    float* out = (float*)d_out;

    // workspace: Q [N*128 f32] | KV2 [N*256 u16] | cnt[N] | slots[N*96] | tk[8]
    float* Q = (float*)d_ws;
    unsigned short* KV2 = (unsigned short*)(Q + (size_t)N_NODES * LATDIM);
    int* cnt   = (int*)(KV2 + (size_t)N_NODES * 256);
    int* slots = cnt + N_NODES;
    int* tk    = slots + (size_t)N_NODES * SLOT_CAP;

    hipMemsetAsync(cnt, 0, sizeof(int) * N_NODES, stream);
    hipMemsetAsync(tk, 0, sizeof(int) * 8, stream);

    // grid = resident capacity (queried once; host-side, graph-safe)
    static int nblk = 0;
    if (nblk == 0) {
        int per_cu = 0;
        hipError_t e = hipOccupancyMaxActiveBlocksPerMultiprocessor(
            &per_cu, reinterpret_cast<const void*>(persist_kernel), BLOCK_T, 0);
        if (e != hipSuccess || per_cu < 1) per_cu = 1;
        nblk = per_cu * 256;
        if (nblk > 2048) nblk = 2048;
    }

    void* args[] = { (void*)&embeds, (void*)&qW, (void*)&kW, (void*)&vW,
                     (void*)&rows, (void*)&cols, (void*)&cnt, (void*)&slots,
                     (void*)&tk, (void*)&Q, (void*)&KV2, (void*)&out };
    hipLaunchCooperativeKernel(reinterpret_cast<const void*>(persist_kernel),
                               dim3(nblk), dim3(BLOCK_T), args, 0u, stream);
}

// Round 3
// 236.858 us; speedup vs baseline: 1.5152x; 1.5152x over previous
//
#include <hip/hip_runtime.h>
#include <hip/hip_bf16.h>

#define N_NODES 50000
#define N_EDGES 800000
#define LATDIM 128
#define HEAD 4
#define SLOT_CAP 96

typedef __attribute__((ext_vector_type(8))) short short8;
typedef __attribute__((ext_vector_type(4))) float floatx4;

// ---------------------------------------------------------------------------
// fp32 -> bf16 helpers (RNE via bit math; inputs are finite)
// ---------------------------------------------------------------------------
__device__ __forceinline__ unsigned bf16_rne_bits(float x) {
    unsigned u = __builtin_bit_cast(unsigned, x);
    return (u + 0x7fffu + ((u >> 16) & 1u)) & 0xffff0000u;
}
__device__ __forceinline__ void split_bf16(float x, short& hi, short& lo) {
    unsigned hb = bf16_rne_bits(x);
    hi = (short)(hb >> 16);
    float hf = __builtin_bit_cast(float, hb);
    unsigned lb = bf16_rne_bits(x - hf);
    lo = (short)(lb >> 16);
}

// ---------------------------------------------------------------------------
// Merged scatter+gemm, restructured for occupancy:
//   blocks [0, SCAT_UNITS): slotted edge scatter (atomic bump), 256-thr units.
//   blocks >= SCAT_UNITS: gemm. 256 threads = 4 waves, ONE projection per
//     block (which = b%3 so the 3 projections of the same 32 rows are
//     dispatch-adjacent -> E rows L2-hot), 32-row A-tile in LDS (17.4 KB),
//     each wave owns a 32-col stripe. B-fragments are loaded from fp32 W
//     (L2-resident) with tIdx-OUTER structure so only 8 short8 (32 VGPR)
//     of B are live at a time. Small blocks + low VGPR/LDS -> ~28 waves/CU
//     resident (vs 9.6 in the 768-thread version), hiding the stage/load
//     latency that dominated (all pipes were <15% busy).
// Output: Q fp32 [N][128]; K/V as bf16 in KV2[n][256]:
//   KV2[n][h*64 + d]      = K[n][h*32+d]   (d in [0,32))
//   KV2[n][h*64 + 32 + d] = V[n][h*32+d]
// ---------------------------------------------------------------------------
#define SCAT_UNITS ((N_EDGES / 4 + 255) / 256)        // 782
#define TILES_PER_PROJ ((N_NODES + 31) / 32)          // 1563
#define GEMM_BLOCKS (3 * TILES_PER_PROJ)              // 4689
#define LDSP 136   // shorts per LDS row (128 + 8 pad)

__global__ __launch_bounds__(256) void gemm_scatter_kernel(
    const float* __restrict__ E,
    const float* __restrict__ qW, const float* __restrict__ kW,
    const float* __restrict__ vW,
    const int* __restrict__ rows, const int* __restrict__ cols,
    int* __restrict__ cnt, int* __restrict__ slots,
    float* __restrict__ Q, unsigned short* __restrict__ KV2)
{
    __shared__ short AhL[32 * LDSP];
    __shared__ short AlL[32 * LDSP];

    if (blockIdx.x < SCAT_UNITS) {
        // ---- edge scatter: slots[r*96 + p] = c, p from per-node atomic bump
        const int t = blockIdx.x * 256 + threadIdx.x;
        if (t < N_EDGES / 4) {
            int4 r = ((const int4*)rows)[t];
            int4 c = ((const int4*)cols)[t];
            int p;
            p = atomicAdd(&cnt[r.x], 1);
            if (p < SLOT_CAP) slots[(size_t)r.x * SLOT_CAP + p] = c.x;
            p = atomicAdd(&cnt[r.y], 1);
            if (p < SLOT_CAP) slots[(size_t)r.y * SLOT_CAP + p] = c.y;
            p = atomicAdd(&cnt[r.z], 1);
            if (p < SLOT_CAP) slots[(size_t)r.z * SLOT_CAP + p] = c.z;
            p = atomicAdd(&cnt[r.w], 1);
            if (p < SLOT_CAP) slots[(size_t)r.w * SLOT_CAP + p] = c.w;
        }
        return;
    }

    // ---- gemm part ----
    const int b = blockIdx.x - SCAT_UNITS;
    const int which = b % 3;                 // 0=Q, 1=K, 2=V
    const int tile  = b / 3;
    const int r_base = tile * 32;

    // stage + convert: 32 rows x 32 float4 = 1024 chunks, 4 per thread
#pragma unroll 4
    for (int chnk = threadIdx.x; chnk < 1024; chnk += 256) {
        const int row = chnk >> 5, c4 = chnk & 31;
        int grow = r_base + row;
        if (grow > N_NODES - 1) grow = N_NODES - 1;
        float4 x = ((const float4*)E)[(size_t)grow * 32 + c4];
        short h0, l0, h1, l1, h2, l2, h3, l3;
        split_bf16(x.x, h0, l0);
        split_bf16(x.y, h1, l1);
        split_bf16(x.z, h2, l2);
        split_bf16(x.w, h3, l3);
        *(short4*)(AhL + row * LDSP + c4 * 4) = make_short4(h0, h1, h2, h3);
        *(short4*)(AlL + row * LDSP + c4 * 4) = make_short4(l0, l1, l2, l3);
    }
    __syncthreads();

    const int wave = threadIdx.x >> 6;       // 0..3 -> 32-col stripe
    const int lane = threadIdx.x & 63;
    const int n_base = wave * 32;
    const int ln = lane & 15;
    const int q  = lane >> 4;
    const float* W = (which == 0) ? qW : (which == 1) ? kW : vW;
    const int vs = (which == 2) ? 32 : 0;

#pragma unroll
    for (int tIdx = 0; tIdx < 2; ++tIdx) {
        // B fragments for this 16-col half-stripe: 8 short8 (32 VGPR) live
        short8 Bh[4], Bl[4];
#pragma unroll
        for (int c = 0; c < 4; ++c)
#pragma unroll
            for (int j = 0; j < 8; ++j) {
                float w = W[(c * 32 + q * 8 + j) * 128 + n_base + tIdx * 16 + ln];
                short hi, lo;
                split_bf16(w, hi, lo);
                Bh[c][j] = hi;
                Bl[c][j] = lo;
            }

        const int cc = n_base + tIdx * 16 + ln;

#pragma unroll
        for (int rt = 0; rt < 2; ++rt) {
            const short* ah = AhL + (rt * 16 + ln) * LDSP + q * 8;
            const short* al = AlL + (rt * 16 + ln) * LDSP + q * 8;

            floatx4 acc = {0.f, 0.f, 0.f, 0.f};
#pragma unroll
            for (int c = 0; c < 4; ++c) {
                short8 Ah = *(const short8*)(ah + c * 32);
                short8 Al = *(const short8*)(al + c * 32);
                acc = __builtin_amdgcn_mfma_f32_16x16x32_bf16(Ah, Bh[c], acc, 0, 0, 0);
                acc = __builtin_amdgcn_mfma_f32_16x16x32_bf16(Ah, Bl[c], acc, 0, 0, 0);
                acc = __builtin_amdgcn_mfma_f32_16x16x32_bf16(Al, Bh[c], acc, 0, 0, 0);
            }

            const int r0 = r_base + rt * 16;
#pragma unroll
            for (int r = 0; r < 4; ++r) {
                const int row = r0 + q * 4 + r;
                if (row >= N_NODES) continue;
                if (which == 0) {
                    Q[(size_t)row * 128 + cc] = acc[r];
                } else {
                    KV2[(size_t)row * 256 + (cc >> 5) * 64 + (cc & 31) + vs] =
                        (unsigned short)(bf16_rne_bits(acc[r]) >> 16);
                }
            }
        }
    }
}

// ---------------------------------------------------------------------------
// L3 fused: one wave per node; lane = (el, h, s) = (edge slot 0..7,
// head 0..3, half 0..1). Each lane owns 16 dims of head h. Dot = in-lane
// 16-dim partial + one shfl_xor(1). exp once per (e,h) pair. V accumulated
// in-lane; epilogue butterfly over the 8 el-lanes (masks 8,16,32).
// ---------------------------------------------------------------------------
__global__ __launch_bounds__(256) void fused_kernel(
    const float* __restrict__ Q,
    const unsigned short* __restrict__ KV2,
    const int* __restrict__ cnt,
    const int* __restrict__ slots,
    float* __restrict__ out)
{
    const int n = blockIdx.x * 4 + (threadIdx.x >> 6);
    if (n >= N_NODES) return;
    const int lane = threadIdx.x & 63;
    const int s  = lane & 1;
    const int h  = (lane >> 1) & 3;
    const int el = lane >> 3;

    int deg = cnt[n];
    if (deg > SLOT_CAP) deg = SLOT_CAP;

    float qv[16];
    {
        const float4* qp = (const float4*)(Q + (size_t)n * 128 + h * 32 + s * 16);
#pragma unroll
        for (int j = 0; j < 4; ++j) {
            float4 t = qp[j];
            qv[4 * j + 0] = t.x; qv[4 * j + 1] = t.y;
            qv[4 * j + 2] = t.z; qv[4 * j + 3] = t.w;
        }
    }

    float acc[16];
#pragma unroll
    for (int j = 0; j < 16; ++j) acc[j] = 0.f;
    float norm = 0.f;

    const int* srow = slots + (size_t)n * SLOT_CAP;

    for (int i = 0; i < deg; i += 8) {
        const int e = i + el;
        if (e < deg) {
            const int col = srow[e];
            const unsigned short* kp = KV2 + (size_t)col * 256 + h * 64 + s * 16;
            uint4 k0 = *(const uint4*)(kp);
            uint4 k1 = *(const uint4*)(kp + 8);
            uint4 v0 = *(const uint4*)(kp + 32);
            uint4 v1 = *(const uint4*)(kp + 40);

            unsigned kw[8] = {k0.x, k0.y, k0.z, k0.w, k1.x, k1.y, k1.z, k1.w};
            float p = 0.f;
#pragma unroll
            for (int d = 0; d < 8; ++d) {
                float flo = __builtin_bit_cast(float, kw[d] << 16);
                float fhi = __builtin_bit_cast(float, kw[d] & 0xffff0000u);
                p += qv[2 * d] * flo + qv[2 * d + 1] * fhi;
            }
            p += __shfl_xor(p, 1);   // combine the two halves of this head

            float a = expf(fminf(fmaxf(p, -10.0f), 10.0f));
            norm += a;

            unsigned vw[8] = {v0.x, v0.y, v0.z, v0.w, v1.x, v1.y, v1.z, v1.w};
#pragma unroll
            for (int d = 0; d < 8; ++d) {
                float flo = __builtin_bit_cast(float, vw[d] << 16);
                float fhi = __builtin_bit_cast(float, vw[d] & 0xffff0000u);
                acc[2 * d]     += a * flo;
                acc[2 * d + 1] += a * fhi;
            }
        }
    }

    // reduce over the 8 edge-slot lanes (all lanes active here)
#pragma unroll
    for (int m = 8; m <= 32; m <<= 1) {
        norm += __shfl_xor(norm, m, 64);
#pragma unroll
        for (int j = 0; j < 16; ++j) acc[j] += __shfl_xor(acc[j], m, 64);
    }

    if (el == 0) {
        const float inv = 1.0f / (norm + 1e-8f);
        float4* op = (float4*)(out + (size_t)n * 128 + h * 32 + s * 16);
#pragma unroll
        for (int j = 0; j < 4; ++j)
            op[j] = make_float4(acc[4 * j] * inv, acc[4 * j + 1] * inv,
                                acc[4 * j + 2] * inv, acc[4 * j + 3] * inv);
    }
}

// ---------------------------------------------------------------------------
extern "C" void kernel_launch(void* const* d_in, const int* in_sizes, int n_in,
                              void* d_out, int out_size, void* d_ws, size_t ws_size,
                              hipStream_t stream) {
    const float* embeds = (const float*)d_in[0];
    const float* qW     = (const float*)d_in[1];
    const float* kW     = (const float*)d_in[2];
    const float* vW     = (const float*)d_in[3];
    const int*   rows   = (const int*)d_in[4];
    const int*   cols   = (const int*)d_in[5];
    float* out = (float*)d_out;

    // workspace layout: Q [N*128 f32] | KV2 [N*256 u16] | cnt[N] | slots[N*96]
    float* Q = (float*)d_ws;
    unsigned short* KV2 = (unsigned short*)(Q + (size_t)N_NODES * LATDIM);
    int* cnt   = (int*)(KV2 + (size_t)N_NODES * 256);
    int* slots = cnt + N_NODES;

    hipMemsetAsync(cnt, 0, sizeof(int) * N_NODES, stream);

    gemm_scatter_kernel<<<SCAT_UNITS + GEMM_BLOCKS, 256, 0, stream>>>(
        embeds, qW, kW, vW, rows, cols, cnt, slots, Q, KV2);

    fused_kernel<<<(N_NODES + 3) / 4, 256, 0, stream>>>(
        Q, KV2, cnt, slots, out);
}

// Round 4
// 203.652 us; speedup vs baseline: 1.7623x; 1.1631x over previous
//
#include <hip/hip_runtime.h>
#include <hip/hip_bf16.h>

#define N_NODES 50000
#define N_EDGES 800000
#define LATDIM 128
#define HEAD 4
#define SLOT_CAP 96

typedef __attribute__((ext_vector_type(8))) short short8;
typedef __attribute__((ext_vector_type(4))) float floatx4;

// ---------------------------------------------------------------------------
// fp32 -> bf16 helpers (RNE via bit math; inputs are finite)
// ---------------------------------------------------------------------------
__device__ __forceinline__ unsigned bf16_rne_bits(float x) {
    unsigned u = __builtin_bit_cast(unsigned, x);
    return (u + 0x7fffu + ((u >> 16) & 1u)) & 0xffff0000u;
}
__device__ __forceinline__ void split_bf16(float x, short& hi, short& lo) {
    unsigned hb = bf16_rne_bits(x);
    hi = (short)(hb >> 16);
    float hf = __builtin_bit_cast(float, hb);
    unsigned lb = bf16_rne_bits(x - hf);
    lo = (short)(lb >> 16);
}

// ---------------------------------------------------------------------------
// init kernel (replaces the cnt memset launch, so packW is "free"):
//   blocks [0,192): pack fp32 W -> B-fragment-order hi/lo bf16 (Whi/Wlo).
//   blocks [192,388): zero cnt.
// Fragment order: Whi[which*16384 + ((c*128+n)*4+q)*8 + j] = W[c*32+q*8+j][n]
// so a gemm lane (ln,q) loads its 8-k fragment as ONE 16-B vector load.
// ---------------------------------------------------------------------------
__global__ __launch_bounds__(256) void init_kernel(
    const float* __restrict__ qW, const float* __restrict__ kW,
    const float* __restrict__ vW,
    short* __restrict__ Whi, short* __restrict__ Wlo,
    int* __restrict__ cnt)
{
    const int b = blockIdx.x;
    if (b < 192) {
        const int which = b >> 6;
        const float* W = (which == 0) ? qW : (which == 1) ? kW : vW;
        const int t = (b & 63) * 256 + threadIdx.x;   // [0, 16384)
        const int k = t >> 7, n = t & 127;
        const int c = k >> 5, q = (k >> 3) & 3, j = k & 7;
        short hi, lo;
        split_bf16(W[k * 128 + n], hi, lo);
        const int dst = which * 16384 + ((c * 128 + n) * 4 + q) * 8 + j;
        Whi[dst] = hi;
        Wlo[dst] = lo;
    } else {
        const int t = (b - 192) * 256 + threadIdx.x;
        if (t < N_NODES) cnt[t] = 0;
    }
}

// ---------------------------------------------------------------------------
// Merged scatter+gemm with 1:2 interleave (b%3==0 -> scatter unit b/3):
// latency-bound atomic scatter waves co-reside with gemm waves on every CU
// from the first scheduling round.
// gemm: 256 thr = 4 waves, 32-row A-tile staged ONCE (fp32 E hi/lo-split
// inline, 17.4 KB LDS), each wave owns a 32-col stripe and loops over all 3
// projections; B fragments are single 16-B vector loads from packed Whi/Wlo
// (L2-hot, 768 KB total). unroll(1) on which/tIdx keeps only 8 short8 of B
// live -> ~60 VGPR -> up to 8 blocks/CU.
// Output: Q fp32 [N][128]; K/V as bf16 in KV2[n][256]:
//   KV2[n][h*64 + d]      = K[n][h*32+d]   (d in [0,32))
//   KV2[n][h*64 + 32 + d] = V[n][h*32+d]
// ---------------------------------------------------------------------------
#define SCAT_UNITS ((N_EDGES / 4 + 255) / 256)        // 782
#define GEMM_TILES ((N_NODES + 31) / 32)              // 1563
#define TOTAL_BLOCKS (3 * SCAT_UNITS)                 // 2346
#define LDSP 136   // shorts per LDS row (128 + 8 pad)

__global__ __launch_bounds__(256) void gemm_scatter_kernel(
    const float* __restrict__ E,
    const short* __restrict__ Whi, const short* __restrict__ Wlo,
    const int* __restrict__ rows, const int* __restrict__ cols,
    int* __restrict__ cnt, int* __restrict__ slots,
    float* __restrict__ Q, unsigned short* __restrict__ KV2)
{
    __shared__ short AhL[32 * LDSP];
    __shared__ short AlL[32 * LDSP];

    const int b = blockIdx.x;
    const int r3 = b % 3;

    if (r3 == 0) {
        // ---- edge scatter: slots[r*96 + p] = c, p from per-node atomic bump
        const int t = (b / 3) * 256 + threadIdx.x;
        if (t < N_EDGES / 4) {
            int4 r = ((const int4*)rows)[t];
            int4 c = ((const int4*)cols)[t];
            int p;
            p = atomicAdd(&cnt[r.x], 1);
            if (p < SLOT_CAP) slots[(size_t)r.x * SLOT_CAP + p] = c.x;
            p = atomicAdd(&cnt[r.y], 1);
            if (p < SLOT_CAP) slots[(size_t)r.y * SLOT_CAP + p] = c.y;
            p = atomicAdd(&cnt[r.z], 1);
            if (p < SLOT_CAP) slots[(size_t)r.z * SLOT_CAP + p] = c.z;
            p = atomicAdd(&cnt[r.w], 1);
            if (p < SLOT_CAP) slots[(size_t)r.w * SLOT_CAP + p] = c.w;
        }
        return;
    }

    // ---- gemm part: tile index from the non-scatter blocks ----
    const int tile = 2 * (b / 3) + (r3 - 1);
    if (tile >= GEMM_TILES) return;
    const int r_base = tile * 32;

    // stage + convert: 32 rows x 32 float4 = 1024 chunks, 4 per thread
#pragma unroll 4
    for (int chnk = threadIdx.x; chnk < 1024; chnk += 256) {
        const int row = chnk >> 5, c4 = chnk & 31;
        int grow = r_base + row;
        if (grow > N_NODES - 1) grow = N_NODES - 1;
        float4 x = ((const float4*)E)[(size_t)grow * 32 + c4];
        short h0, l0, h1, l1, h2, l2, h3, l3;
        split_bf16(x.x, h0, l0);
        split_bf16(x.y, h1, l1);
        split_bf16(x.z, h2, l2);
        split_bf16(x.w, h3, l3);
        *(short4*)(AhL + row * LDSP + c4 * 4) = make_short4(h0, h1, h2, h3);
        *(short4*)(AlL + row * LDSP + c4 * 4) = make_short4(l0, l1, l2, l3);
    }
    __syncthreads();

    const int wave = threadIdx.x >> 6;       // 0..3 -> 32-col stripe
    const int lane = threadIdx.x & 63;
    const int n_base = wave * 32;
    const int ln = lane & 15;
    const int q  = lane >> 4;

#pragma unroll 1
    for (int which = 0; which < 3; ++which) {
        const int vs = (which == 2) ? 32 : 0;
#pragma unroll 1
        for (int tIdx = 0; tIdx < 2; ++tIdx) {
            // B fragments: 4 pairs of 16-B vector loads (L2-hot packed W)
            short8 Bh[4], Bl[4];
#pragma unroll
            for (int c = 0; c < 4; ++c) {
                const int off = which * 16384 +
                                ((c * 128 + n_base + tIdx * 16 + ln) * 4 + q) * 8;
                Bh[c] = *(const short8*)(Whi + off);
                Bl[c] = *(const short8*)(Wlo + off);
            }
            const int cc = n_base + tIdx * 16 + ln;

#pragma unroll
            for (int rt = 0; rt < 2; ++rt) {
                const short* ah = AhL + (rt * 16 + ln) * LDSP + q * 8;
                const short* al = AlL + (rt * 16 + ln) * LDSP + q * 8;

                floatx4 acc = {0.f, 0.f, 0.f, 0.f};
#pragma unroll
                for (int c = 0; c < 4; ++c) {
                    short8 Ah = *(const short8*)(ah + c * 32);
                    short8 Al = *(const short8*)(al + c * 32);
                    acc = __builtin_amdgcn_mfma_f32_16x16x32_bf16(Ah, Bh[c], acc, 0, 0, 0);
                    acc = __builtin_amdgcn_mfma_f32_16x16x32_bf16(Ah, Bl[c], acc, 0, 0, 0);
                    acc = __builtin_amdgcn_mfma_f32_16x16x32_bf16(Al, Bh[c], acc, 0, 0, 0);
                }

                const int r0 = r_base + rt * 16;
#pragma unroll
                for (int r = 0; r < 4; ++r) {
                    const int row = r0 + q * 4 + r;
                    if (row >= N_NODES) continue;
                    if (which == 0) {
                        Q[(size_t)row * 128 + cc] = acc[r];
                    } else {
                        KV2[(size_t)row * 256 + (cc >> 5) * 64 + (cc & 31) + vs] =
                            (unsigned short)(bf16_rne_bits(acc[r]) >> 16);
                    }
                }
            }
        }
    }
}

// ---------------------------------------------------------------------------
// L3 fused: one wave per node; lane = (el, h, s) = (edge slot 0..7,
// head 0..3, half 0..1). Each lane owns 16 dims of head h. Dot = in-lane
// 16-dim partial + one shfl_xor(1). exp once per (e,h) pair. V accumulated
// in-lane; epilogue butterfly over the 8 el-lanes (masks 8,16,32).
// ---------------------------------------------------------------------------
__global__ __launch_bounds__(256) void fused_kernel(
    const float* __restrict__ Q,
    const unsigned short* __restrict__ KV2,
    const int* __restrict__ cnt,
    const int* __restrict__ slots,
    float* __restrict__ out)
{
    const int n = blockIdx.x * 4 + (threadIdx.x >> 6);
    if (n >= N_NODES) return;
    const int lane = threadIdx.x & 63;
    const int s  = lane & 1;
    const int h  = (lane >> 1) & 3;
    const int el = lane >> 3;

    int deg = cnt[n];
    if (deg > SLOT_CAP) deg = SLOT_CAP;

    float qv[16];
    {
        const float4* qp = (const float4*)(Q + (size_t)n * 128 + h * 32 + s * 16);
#pragma unroll
        for (int j = 0; j < 4; ++j) {
            float4 t = qp[j];
            qv[4 * j + 0] = t.x; qv[4 * j + 1] = t.y;
            qv[4 * j + 2] = t.z; qv[4 * j + 3] = t.w;
        }
    }

    float acc[16];
#pragma unroll
    for (int j = 0; j < 16; ++j) acc[j] = 0.f;
    float norm = 0.f;

    const int* srow = slots + (size_t)n * SLOT_CAP;

    for (int i = 0; i < deg; i += 8) {
        const int e = i + el;
        if (e < deg) {
            const int col = srow[e];
            const unsigned short* kp = KV2 + (size_t)col * 256 + h * 64 + s * 16;
            uint4 k0 = *(const uint4*)(kp);
            uint4 k1 = *(const uint4*)(kp + 8);
            uint4 v0 = *(const uint4*)(kp + 32);
            uint4 v1 = *(const uint4*)(kp + 40);

            unsigned kw[8] = {k0.x, k0.y, k0.z, k0.w, k1.x, k1.y, k1.z, k1.w};
            float p = 0.f;
#pragma unroll
            for (int d = 0; d < 8; ++d) {
                float flo = __builtin_bit_cast(float, kw[d] << 16);
                float fhi = __builtin_bit_cast(float, kw[d] & 0xffff0000u);
                p += qv[2 * d] * flo + qv[2 * d + 1] * fhi;
            }
            p += __shfl_xor(p, 1);   // combine the two halves of this head

            float a = expf(fminf(fmaxf(p, -10.0f), 10.0f));
            norm += a;

            unsigned vw[8] = {v0.x, v0.y, v0.z, v0.w, v1.x, v1.y, v1.z, v1.w};
#pragma unroll
            for (int d = 0; d < 8; ++d) {
                float flo = __builtin_bit_cast(float, vw[d] << 16);
                float fhi = __builtin_bit_cast(float, vw[d] & 0xffff0000u);
                acc[2 * d]     += a * flo;
                acc[2 * d + 1] += a * fhi;
            }
        }
    }

    // reduce over the 8 edge-slot lanes (all lanes active here)
#pragma unroll
    for (int m = 8; m <= 32; m <<= 1) {
        norm += __shfl_xor(norm, m, 64);
#pragma unroll
        for (int j = 0; j < 16; ++j) acc[j] += __shfl_xor(acc[j], m, 64);
    }

    if (el == 0) {
        const float inv = 1.0f / (norm + 1e-8f);
        float4* op = (float4*)(out + (size_t)n * 128 + h * 32 + s * 16);
#pragma unroll
        for (int j = 0; j < 4; ++j)
            op[j] = make_float4(acc[4 * j] * inv, acc[4 * j + 1] * inv,
                                acc[4 * j + 2] * inv, acc[4 * j + 3] * inv);
    }
}

// ---------------------------------------------------------------------------
extern "C" void kernel_launch(void* const* d_in, const int* in_sizes, int n_in,
                              void* d_out, int out_size, void* d_ws, size_t ws_size,
                              hipStream_t stream) {
    const float* embeds = (const float*)d_in[0];
    const float* qW     = (const float*)d_in[1];
    const float* kW     = (const float*)d_in[2];
    const float* vW     = (const float*)d_in[3];
    const int*   rows   = (const int*)d_in[4];
    const int*   cols   = (const int*)d_in[5];
    float* out = (float*)d_out;

    // workspace: Q [N*128 f32] | KV2 [N*256 u16] | cnt[N] | slots[N*96] |
    //            Whi[3*16384] | Wlo[3*16384]
    float* Q = (float*)d_ws;
    unsigned short* KV2 = (unsigned short*)(Q + (size_t)N_NODES * LATDIM);
    int* cnt   = (int*)(KV2 + (size_t)N_NODES * 256);
    int* slots = cnt + N_NODES;
    short* Whi = (short*)(slots + (size_t)N_NODES * SLOT_CAP);
    short* Wlo = Whi + 3 * 16384;

    // init: packW (192 blocks) + zero cnt (196 blocks) — replaces the memset
    init_kernel<<<192 + (N_NODES + 255) / 256, 256, 0, stream>>>(
        qW, kW, vW, Whi, Wlo, cnt);

    gemm_scatter_kernel<<<TOTAL_BLOCKS, 256, 0, stream>>>(
        embeds, Whi, Wlo, rows, cols, cnt, slots, Q, KV2);

    fused_kernel<<<(N_NODES + 3) / 4, 256, 0, stream>>>(
        Q, KV2, cnt, slots, out);
}

// Round 5
// 198.703 us; speedup vs baseline: 1.8062x; 1.0249x over previous
//
#include <hip/hip_runtime.h>
#include <hip/hip_bf16.h>

#define N_NODES 50000
#define N_EDGES 800000
#define LATDIM 128
#define HEAD 4
#define SLOT_CAP 96

typedef __attribute__((ext_vector_type(8))) short short8;
typedef __attribute__((ext_vector_type(8))) _Float16 half8;
typedef __attribute__((ext_vector_type(4))) float floatx4;

// ---------------------------------------------------------------------------
// fp32 -> bf16 helpers (RNE via bit math; inputs are finite)
// ---------------------------------------------------------------------------
__device__ __forceinline__ unsigned bf16_rne_bits(float x) {
    unsigned u = __builtin_bit_cast(unsigned, x);
    return (u + 0x7fffu + ((u >> 16) & 1u)) & 0xffff0000u;
}
__device__ __forceinline__ void split_bf16(float x, short& hi, short& lo) {
    unsigned hb = bf16_rne_bits(x);
    hi = (short)(hb >> 16);
    float hf = __builtin_bit_cast(float, hb);
    unsigned lb = bf16_rne_bits(x - hf);
    lo = (short)(lb >> 16);
}

// ---------------------------------------------------------------------------
// init kernel (replaces the cnt memset launch, so packW is "free"):
//   blocks [0,192): pack fp32 W -> B-fragment-order hi/lo bf16 (Whi/Wlo).
//   blocks [192,388): zero cnt.
// Fragment order: Whi[which*16384 + ((c*128+n)*4+q)*8 + j] = W[c*32+q*8+j][n]
// so a gemm lane (ln,q) loads its 8-k fragment as ONE 16-B vector load.
// ---------------------------------------------------------------------------
__global__ __launch_bounds__(256) void init_kernel(
    const float* __restrict__ qW, const float* __restrict__ kW,
    const float* __restrict__ vW,
    short* __restrict__ Whi, short* __restrict__ Wlo,
    int* __restrict__ cnt)
{
    const int b = blockIdx.x;
    if (b < 192) {
        const int which = b >> 6;
        const float* W = (which == 0) ? qW : (which == 1) ? kW : vW;
        const int t = (b & 63) * 256 + threadIdx.x;   // [0, 16384)
        const int k = t >> 7, n = t & 127;
        const int c = k >> 5, q = (k >> 3) & 3, j = k & 7;
        short hi, lo;
        split_bf16(W[k * 128 + n], hi, lo);
        const int dst = which * 16384 + ((c * 128 + n) * 4 + q) * 8 + j;
        Whi[dst] = hi;
        Wlo[dst] = lo;
    } else {
        const int t = (b - 192) * 256 + threadIdx.x;
        if (t < N_NODES) cnt[t] = 0;
    }
}

// ---------------------------------------------------------------------------
// Merged scatter+gemm with 1:2 interleave (b%3==0 -> scatter unit b/3).
// gemm: 256 thr = 4 waves, 32-row A-tile staged ONCE in LDS; A-fragments
// hoisted to registers ONCE (16 short8 pairs, 64 VGPR) -> LDS reads drop
// 96 -> 32 per lane (the inner loop was ds_read-bound: 96x12cyc > 144x5cyc
// MFMA). Each wave owns a 32-col stripe, loops 3 projections x 2 halves;
// B frags are 16-B vector loads from packed Whi/Wlo (L2-hot).
// Output: Q fp32 [N][128]; K/V as *f16* in KV2[n][256]:
//   KV2[n][h*64 + d]      = K[n][h*32+d]   (d in [0,32))
//   KV2[n][h*64 + 32 + d] = V[n][h*32+d]
// (f16, not bf16: more mantissa for the same bytes; enables v_fma_mix in
//  the fused consumer with zero unpack VALU.)
// ---------------------------------------------------------------------------
#define SCAT_UNITS ((N_EDGES / 4 + 255) / 256)        // 782
#define GEMM_TILES ((N_NODES + 31) / 32)              // 1563
#define TOTAL_BLOCKS (3 * SCAT_UNITS)                 // 2346
#define LDSP 136   // shorts per LDS row (128 + 8 pad)

__global__ __launch_bounds__(256) void gemm_scatter_kernel(
    const float* __restrict__ E,
    const short* __restrict__ Whi, const short* __restrict__ Wlo,
    const int* __restrict__ rows, const int* __restrict__ cols,
    int* __restrict__ cnt, int* __restrict__ slots,
    float* __restrict__ Q, unsigned short* __restrict__ KV2)
{
    __shared__ short AhL[32 * LDSP];
    __shared__ short AlL[32 * LDSP];

    const int b = blockIdx.x;
    const int r3 = b % 3;

    if (r3 == 0) {
        // ---- edge scatter: slots[r*96 + p] = c, p from per-node atomic bump
        const int t = (b / 3) * 256 + threadIdx.x;
        if (t < N_EDGES / 4) {
            int4 r = ((const int4*)rows)[t];
            int4 c = ((const int4*)cols)[t];
            int p;
            p = atomicAdd(&cnt[r.x], 1);
            if (p < SLOT_CAP) slots[(size_t)r.x * SLOT_CAP + p] = c.x;
            p = atomicAdd(&cnt[r.y], 1);
            if (p < SLOT_CAP) slots[(size_t)r.y * SLOT_CAP + p] = c.y;
            p = atomicAdd(&cnt[r.z], 1);
            if (p < SLOT_CAP) slots[(size_t)r.z * SLOT_CAP + p] = c.z;
            p = atomicAdd(&cnt[r.w], 1);
            if (p < SLOT_CAP) slots[(size_t)r.w * SLOT_CAP + p] = c.w;
        }
        return;
    }

    // ---- gemm part: tile index from the non-scatter blocks ----
    const int tile = 2 * (b / 3) + (r3 - 1);
    if (tile >= GEMM_TILES) return;
    const int r_base = tile * 32;

    // stage + convert: 32 rows x 32 float4 = 1024 chunks, 4 per thread
#pragma unroll 4
    for (int chnk = threadIdx.x; chnk < 1024; chnk += 256) {
        const int row = chnk >> 5, c4 = chnk & 31;
        int grow = r_base + row;
        if (grow > N_NODES - 1) grow = N_NODES - 1;
        float4 x = ((const float4*)E)[(size_t)grow * 32 + c4];
        short h0, l0, h1, l1, h2, l2, h3, l3;
        split_bf16(x.x, h0, l0);
        split_bf16(x.y, h1, l1);
        split_bf16(x.z, h2, l2);
        split_bf16(x.w, h3, l3);
        *(short4*)(AhL + row * LDSP + c4 * 4) = make_short4(h0, h1, h2, h3);
        *(short4*)(AlL + row * LDSP + c4 * 4) = make_short4(l0, l1, l2, l3);
    }
    __syncthreads();

    const int wave = threadIdx.x >> 6;       // 0..3 -> 32-col stripe
    const int lane = threadIdx.x & 63;
    const int n_base = wave * 32;
    const int ln = lane & 15;
    const int q  = lane >> 4;

    // hoist all A fragments to registers (read LDS exactly once per frag)
    short8 Ah[2][4], Al[2][4];
#pragma unroll
    for (int rt = 0; rt < 2; ++rt)
#pragma unroll
        for (int c = 0; c < 4; ++c) {
            const int ao = (rt * 16 + ln) * LDSP + q * 8 + c * 32;
            Ah[rt][c] = *(const short8*)(AhL + ao);
            Al[rt][c] = *(const short8*)(AlL + ao);
        }

#pragma unroll 1
    for (int which = 0; which < 3; ++which) {
        const int vs = (which == 2) ? 32 : 0;
#pragma unroll 1
        for (int tIdx = 0; tIdx < 2; ++tIdx) {
            // B fragments: 4 pairs of 16-B vector loads (L2-hot packed W)
            short8 Bh[4], Bl[4];
#pragma unroll
            for (int c = 0; c < 4; ++c) {
                const int off = which * 16384 +
                                ((c * 128 + n_base + tIdx * 16 + ln) * 4 + q) * 8;
                Bh[c] = *(const short8*)(Whi + off);
                Bl[c] = *(const short8*)(Wlo + off);
            }
            const int cc = n_base + tIdx * 16 + ln;

#pragma unroll
            for (int rt = 0; rt < 2; ++rt) {
                floatx4 acc = {0.f, 0.f, 0.f, 0.f};
#pragma unroll
                for (int c = 0; c < 4; ++c) {
                    acc = __builtin_amdgcn_mfma_f32_16x16x32_bf16(Ah[rt][c], Bh[c], acc, 0, 0, 0);
                    acc = __builtin_amdgcn_mfma_f32_16x16x32_bf16(Ah[rt][c], Bl[c], acc, 0, 0, 0);
                    acc = __builtin_amdgcn_mfma_f32_16x16x32_bf16(Al[rt][c], Bh[c], acc, 0, 0, 0);
                }

                const int r0 = r_base + rt * 16;
#pragma unroll
                for (int r = 0; r < 4; ++r) {
                    const int row = r0 + q * 4 + r;
                    if (row >= N_NODES) continue;
                    if (which == 0) {
                        Q[(size_t)row * 128 + cc] = acc[r];
                    } else {
                        KV2[(size_t)row * 256 + (cc >> 5) * 64 + (cc & 31) + vs] =
                            __builtin_bit_cast(unsigned short, (_Float16)acc[r]);
                    }
                }
            }
        }
    }
}

// ---------------------------------------------------------------------------
// L3 fused: one wave per node; lane = (el, h, s) = (edge slot 0..7,
// head 0..3, half 0..1). Each lane owns 16 dims of head h. K/V are f16:
// (float)h * f32 FMAs compile to v_fma_mix_f32 (no unpack VALU). Dot =
// in-lane 16-dim partial + one shfl_xor(1). __expf once per (e,h) pair.
// V accumulated in-lane; epilogue butterfly over the 8 el-lanes.
// ---------------------------------------------------------------------------
__global__ __launch_bounds__(256) void fused_kernel(
    const float* __restrict__ Q,
    const unsigned short* __restrict__ KV2,
    const int* __restrict__ cnt,
    const int* __restrict__ slots,
    float* __restrict__ out)
{
    const int n = blockIdx.x * 4 + (threadIdx.x >> 6);
    if (n >= N_NODES) return;
    const int lane = threadIdx.x & 63;
    const int s  = lane & 1;
    const int h  = (lane >> 1) & 3;
    const int el = lane >> 3;

    int deg = cnt[n];
    if (deg > SLOT_CAP) deg = SLOT_CAP;

    float qv[16];
    {
        const float4* qp = (const float4*)(Q + (size_t)n * 128 + h * 32 + s * 16);
#pragma unroll
        for (int j = 0; j < 4; ++j) {
            float4 t = qp[j];
            qv[4 * j + 0] = t.x; qv[4 * j + 1] = t.y;
            qv[4 * j + 2] = t.z; qv[4 * j + 3] = t.w;
        }
    }

    float acc[16];
#pragma unroll
    for (int j = 0; j < 16; ++j) acc[j] = 0.f;
    float norm = 0.f;

    const int* srow = slots + (size_t)n * SLOT_CAP;

    for (int i = 0; i < deg; i += 8) {
        const int e = i + el;
        if (e < deg) {
            const int col = srow[e];
            const _Float16* kp = (const _Float16*)(KV2 + (size_t)col * 256 + h * 64 + s * 16);
            half8 k0 = *(const half8*)(kp);
            half8 k1 = *(const half8*)(kp + 8);
            half8 v0 = *(const half8*)(kp + 32);
            half8 v1 = *(const half8*)(kp + 40);

            float p = 0.f;
#pragma unroll
            for (int d = 0; d < 8; ++d) {
                p = fmaf((float)k0[d], qv[d], p);
                p = fmaf((float)k1[d], qv[8 + d], p);
            }
            p += __shfl_xor(p, 1);   // combine the two halves of this head

            float a = __expf(fminf(fmaxf(p, -10.0f), 10.0f));
            norm += a;

#pragma unroll
            for (int d = 0; d < 8; ++d) {
                acc[d]     = fmaf((float)v0[d], a, acc[d]);
                acc[8 + d] = fmaf((float)v1[d], a, acc[8 + d]);
            }
        }
    }

    // reduce over the 8 edge-slot lanes (all lanes active here)
#pragma unroll
    for (int m = 8; m <= 32; m <<= 1) {
        norm += __shfl_xor(norm, m, 64);
#pragma unroll
        for (int j = 0; j < 16; ++j) acc[j] += __shfl_xor(acc[j], m, 64);
    }

    if (el == 0) {
        const float inv = 1.0f / (norm + 1e-8f);
        float4* op = (float4*)(out + (size_t)n * 128 + h * 32 + s * 16);
#pragma unroll
        for (int j = 0; j < 4; ++j)
            op[j] = make_float4(acc[4 * j] * inv, acc[4 * j + 1] * inv,
                                acc[4 * j + 2] * inv, acc[4 * j + 3] * inv);
    }
}

// ---------------------------------------------------------------------------
extern "C" void kernel_launch(void* const* d_in, const int* in_sizes, int n_in,
                              void* d_out, int out_size, void* d_ws, size_t ws_size,
                              hipStream_t stream) {
    const float* embeds = (const float*)d_in[0];
    const float* qW     = (const float*)d_in[1];
    const float* kW     = (const float*)d_in[2];
    const float* vW     = (const float*)d_in[3];
    const int*   rows   = (const int*)d_in[4];
    const int*   cols   = (const int*)d_in[5];
    float* out = (float*)d_out;

    // workspace: Q [N*128 f32] | KV2 [N*256 u16] | cnt[N] | slots[N*96] |
    //            Whi[3*16384] | Wlo[3*16384]
    float* Q = (float*)d_ws;
    unsigned short* KV2 = (unsigned short*)(Q + (size_t)N_NODES * LATDIM);
    int* cnt   = (int*)(KV2 + (size_t)N_NODES * 256);
    int* slots = cnt + N_NODES;
    short* Whi = (short*)(slots + (size_t)N_NODES * SLOT_CAP);
    short* Wlo = Whi + 3 * 16384;

    // init: packW (192 blocks) + zero cnt (196 blocks) — replaces the memset
    init_kernel<<<192 + (N_NODES + 255) / 256, 256, 0, stream>>>(
        qW, kW, vW, Whi, Wlo, cnt);

    gemm_scatter_kernel<<<TOTAL_BLOCKS, 256, 0, stream>>>(
        embeds, Whi, Wlo, rows, cols, cnt, slots, Q, KV2);

    fused_kernel<<<(N_NODES + 3) / 4, 256, 0, stream>>>(
        Q, KV2, cnt, slots, out);
}

// Round 6
// 193.365 us; speedup vs baseline: 1.8561x; 1.0276x over previous
//
#include <hip/hip_runtime.h>
#include <hip/hip_bf16.h>

#define N_NODES 50000
#define N_EDGES 800000
#define LATDIM 128
#define HEAD 4
#define SLOT_CAP 96

typedef __attribute__((ext_vector_type(8))) short short8;
typedef __attribute__((ext_vector_type(8))) _Float16 half8;
typedef __attribute__((ext_vector_type(4))) float floatx4;

// ---------------------------------------------------------------------------
// fp32 -> bf16 helpers (RNE via bit math; inputs are finite)
// ---------------------------------------------------------------------------
__device__ __forceinline__ unsigned bf16_rne_bits(float x) {
    unsigned u = __builtin_bit_cast(unsigned, x);
    return (u + 0x7fffu + ((u >> 16) & 1u)) & 0xffff0000u;
}
__device__ __forceinline__ void split_bf16(float x, short& hi, short& lo) {
    unsigned hb = bf16_rne_bits(x);
    hi = (short)(hb >> 16);
    float hf = __builtin_bit_cast(float, hb);
    unsigned lb = bf16_rne_bits(x - hf);
    lo = (short)(lb >> 16);
}

// ---------------------------------------------------------------------------
// init kernel: packW (fragment-order hi/lo bf16) + zero cnt.
// Whi[which*16384 + ((c*128+n)*4+q)*8 + j] = W[c*32+q*8+j][n]
// ---------------------------------------------------------------------------
__global__ __launch_bounds__(256) void init_kernel(
    const float* __restrict__ qW, const float* __restrict__ kW,
    const float* __restrict__ vW,
    short* __restrict__ Whi, short* __restrict__ Wlo,
    int* __restrict__ cnt)
{
    const int b = blockIdx.x;
    if (b < 192) {
        const int which = b >> 6;
        const float* W = (which == 0) ? qW : (which == 1) ? kW : vW;
        const int t = (b & 63) * 256 + threadIdx.x;   // [0, 16384)
        const int k = t >> 7, n = t & 127;
        const int c = k >> 5, q = (k >> 3) & 3, j = k & 7;
        short hi, lo;
        split_bf16(W[k * 128 + n], hi, lo);
        const int dst = which * 16384 + ((c * 128 + n) * 4 + q) * 8 + j;
        Whi[dst] = hi;
        Wlo[dst] = lo;
    } else {
        const int t = (b - 192) * 256 + threadIdx.x;
        if (t < N_NODES) cnt[t] = 0;
    }
}

// ---------------------------------------------------------------------------
// Merged scatter+gemm with 1:2 interleave (b%3==0 -> scatter unit b/3).
// gemm: 256 thr = 4 waves, 32-row A-tile in LDS, packed-B 16-B vector loads.
// NEW: staged coalesced epilogue. Loop order K,V,Q; K/V accs land in a 16 KB
// LDS Stage laid out exactly as the global KV2 rows (32x256 u16), then ONE
// contiguous 16 KB uint4 stream-out (rows r_base..r_base+31 are contiguous
// in KV2[N][256]); Stage is reused for Q (32x128 f32 = 16 KB, same trick).
// Replaces ~96 strided 2-/4-B store instrs per wave with ~8 full-line
// vector stores and kills partial-line writebacks.
// KV2[n][h*64+d] = K[n][h*32+d]; KV2[n][h*64+32+d] = V[n][h*32+d]  (f16)
// ---------------------------------------------------------------------------
#define SCAT_UNITS ((N_EDGES / 4 + 255) / 256)        // 782
#define GEMM_TILES ((N_NODES + 31) / 32)              // 1563
#define TOTAL_BLOCKS (3 * SCAT_UNITS)                 // 2346
#define LDSP 136   // shorts per LDS row (128 + 8 pad)

__global__ __launch_bounds__(256) void gemm_scatter_kernel(
    const float* __restrict__ E,
    const short* __restrict__ Whi, const short* __restrict__ Wlo,
    const int* __restrict__ rows, const int* __restrict__ cols,
    int* __restrict__ cnt, int* __restrict__ slots,
    float* __restrict__ Q, unsigned short* __restrict__ KV2)
{
    __shared__ short AhL[32 * LDSP];
    __shared__ short AlL[32 * LDSP];
    __shared__ unsigned short Stage[32 * 256];   // 16 KB; reused f16 KV / f32 Q

    const int b = blockIdx.x;
    const int r3 = b % 3;

    if (r3 == 0) {
        // ---- edge scatter: slots[r*96 + p] = c, p from per-node atomic bump
        const int t = (b / 3) * 256 + threadIdx.x;
        if (t < N_EDGES / 4) {
            int4 r = ((const int4*)rows)[t];
            int4 c = ((const int4*)cols)[t];
            int p;
            p = atomicAdd(&cnt[r.x], 1);
            if (p < SLOT_CAP) slots[(size_t)r.x * SLOT_CAP + p] = c.x;
            p = atomicAdd(&cnt[r.y], 1);
            if (p < SLOT_CAP) slots[(size_t)r.y * SLOT_CAP + p] = c.y;
            p = atomicAdd(&cnt[r.z], 1);
            if (p < SLOT_CAP) slots[(size_t)r.z * SLOT_CAP + p] = c.z;
            p = atomicAdd(&cnt[r.w], 1);
            if (p < SLOT_CAP) slots[(size_t)r.w * SLOT_CAP + p] = c.w;
        }
        return;
    }

    // ---- gemm part ----
    const int tile = 2 * (b / 3) + (r3 - 1);
    if (tile >= GEMM_TILES) return;
    const int r_base = tile * 32;

    // stage + convert A: 32 rows x 32 float4 = 1024 chunks, 4 per thread
#pragma unroll 4
    for (int chnk = threadIdx.x; chnk < 1024; chnk += 256) {
        const int row = chnk >> 5, c4 = chnk & 31;
        int grow = r_base + row;
        if (grow > N_NODES - 1) grow = N_NODES - 1;
        float4 x = ((const float4*)E)[(size_t)grow * 32 + c4];
        short h0, l0, h1, l1, h2, l2, h3, l3;
        split_bf16(x.x, h0, l0);
        split_bf16(x.y, h1, l1);
        split_bf16(x.z, h2, l2);
        split_bf16(x.w, h3, l3);
        *(short4*)(AhL + row * LDSP + c4 * 4) = make_short4(h0, h1, h2, h3);
        *(short4*)(AlL + row * LDSP + c4 * 4) = make_short4(l0, l1, l2, l3);
    }
    __syncthreads();

    const int wave = threadIdx.x >> 6;       // 0..3 -> 32-col stripe
    const int lane = threadIdx.x & 63;
    const int n_base = wave * 32;
    const int ln = lane & 15;
    const int q  = lane >> 4;

    // ---- K and V into Stage (f16, exact global layout) ----
#pragma unroll 1
    for (int which = 1; which < 3; ++which) {
        const int vs = (which == 2) ? 32 : 0;
#pragma unroll 1
        for (int tIdx = 0; tIdx < 2; ++tIdx) {
            short8 Bh[4], Bl[4];
#pragma unroll
            for (int c = 0; c < 4; ++c) {
                const int off = which * 16384 +
                                ((c * 128 + n_base + tIdx * 16 + ln) * 4 + q) * 8;
                Bh[c] = *(const short8*)(Whi + off);
                Bl[c] = *(const short8*)(Wlo + off);
            }

#pragma unroll
            for (int rt = 0; rt < 2; ++rt) {
                const short* ah = AhL + (rt * 16 + ln) * LDSP + q * 8;
                const short* al = AlL + (rt * 16 + ln) * LDSP + q * 8;
                floatx4 acc = {0.f, 0.f, 0.f, 0.f};
#pragma unroll
                for (int c = 0; c < 4; ++c) {
                    short8 Ah = *(const short8*)(ah + c * 32);
                    short8 Al = *(const short8*)(al + c * 32);
                    acc = __builtin_amdgcn_mfma_f32_16x16x32_bf16(Ah, Bh[c], acc, 0, 0, 0);
                    acc = __builtin_amdgcn_mfma_f32_16x16x32_bf16(Ah, Bl[c], acc, 0, 0, 0);
                    acc = __builtin_amdgcn_mfma_f32_16x16x32_bf16(Al, Bh[c], acc, 0, 0, 0);
                }
#pragma unroll
                for (int r = 0; r < 4; ++r) {
                    const int lr = rt * 16 + q * 4 + r;     // local row 0..31
                    Stage[lr * 256 + wave * 64 + tIdx * 16 + ln + vs] =
                        __builtin_bit_cast(unsigned short, (_Float16)acc[r]);
                }
            }
        }
    }
    __syncthreads();

    // ---- coalesced KV2 stream-out: 16 KB contiguous (guard N boundary) ----
#pragma unroll
    for (int it = 0; it < 4; ++it) {
        const int ch = threadIdx.x + it * 256;      // 16-B chunk index
        const int lr = ch >> 5;                      // 512 B per row
        if (r_base + lr < N_NODES)
            ((uint4*)(KV2 + (size_t)r_base * 256))[ch] = ((const uint4*)Stage)[ch];
    }
    __syncthreads();

    // ---- Q into Stage (f32, exact global layout), then stream-out ----
    {
        const int which = 0;
        float* QS = (float*)Stage;
#pragma unroll 1
        for (int tIdx = 0; tIdx < 2; ++tIdx) {
            short8 Bh[4], Bl[4];
#pragma unroll
            for (int c = 0; c < 4; ++c) {
                const int off = which * 16384 +
                                ((c * 128 + n_base + tIdx * 16 + ln) * 4 + q) * 8;
                Bh[c] = *(const short8*)(Whi + off);
                Bl[c] = *(const short8*)(Wlo + off);
            }
            const int cc = n_base + tIdx * 16 + ln;

#pragma unroll
            for (int rt = 0; rt < 2; ++rt) {
                const short* ah = AhL + (rt * 16 + ln) * LDSP + q * 8;
                const short* al = AlL + (rt * 16 + ln) * LDSP + q * 8;
                floatx4 acc = {0.f, 0.f, 0.f, 0.f};
#pragma unroll
                for (int c = 0; c < 4; ++c) {
                    short8 Ah = *(const short8*)(ah + c * 32);
                    short8 Al = *(const short8*)(al + c * 32);
                    acc = __builtin_amdgcn_mfma_f32_16x16x32_bf16(Ah, Bh[c], acc, 0, 0, 0);
                    acc = __builtin_amdgcn_mfma_f32_16x16x32_bf16(Ah, Bl[c], acc, 0, 0, 0);
                    acc = __builtin_amdgcn_mfma_f32_16x16x32_bf16(Al, Bh[c], acc, 0, 0, 0);
                }
#pragma unroll
                for (int r = 0; r < 4; ++r) {
                    const int lr = rt * 16 + q * 4 + r;
                    QS[lr * 128 + cc] = acc[r];
                }
            }
        }
    }
    __syncthreads();

#pragma unroll
    for (int it = 0; it < 4; ++it) {
        const int ch = threadIdx.x + it * 256;      // 16-B chunk index
        const int lr = ch >> 5;                      // 512 B per row
        if (r_base + lr < N_NODES)
            ((float4*)(Q + (size_t)r_base * 128))[ch] = ((const float4*)Stage)[ch];
    }
}

// ---------------------------------------------------------------------------
// L3 fused: one wave per node; lane = (el, h, s). K/V f16 -> v_fma_mix FMAs,
// __expf. Dot = in-lane 16-dim partial + shfl_xor(1); epilogue butterfly.
// ---------------------------------------------------------------------------
__global__ __launch_bounds__(256) void fused_kernel(
    const float* __restrict__ Q,
    const unsigned short* __restrict__ KV2,
    const int* __restrict__ cnt,
    const int* __restrict__ slots,
    float* __restrict__ out)
{
    const int n = blockIdx.x * 4 + (threadIdx.x >> 6);
    if (n >= N_NODES) return;
    const int lane = threadIdx.x & 63;
    const int s  = lane & 1;
    const int h  = (lane >> 1) & 3;
    const int el = lane >> 3;

    int deg = cnt[n];
    if (deg > SLOT_CAP) deg = SLOT_CAP;

    float qv[16];
    {
        const float4* qp = (const float4*)(Q + (size_t)n * 128 + h * 32 + s * 16);
#pragma unroll
        for (int j = 0; j < 4; ++j) {
            float4 t = qp[j];
            qv[4 * j + 0] = t.x; qv[4 * j + 1] = t.y;
            qv[4 * j + 2] = t.z; qv[4 * j + 3] = t.w;
        }
    }

    float acc[16];
#pragma unroll
    for (int j = 0; j < 16; ++j) acc[j] = 0.f;
    float norm = 0.f;

    const int* srow = slots + (size_t)n * SLOT_CAP;

    for (int i = 0; i < deg; i += 8) {
        const int e = i + el;
        if (e < deg) {
            const int col = srow[e];
            const _Float16* kp = (const _Float16*)(KV2 + (size_t)col * 256 + h * 64 + s * 16);
            half8 k0 = *(const half8*)(kp);
            half8 k1 = *(const half8*)(kp + 8);
            half8 v0 = *(const half8*)(kp + 32);
            half8 v1 = *(const half8*)(kp + 40);

            float p = 0.f;
#pragma unroll
            for (int d = 0; d < 8; ++d) {
                p = fmaf((float)k0[d], qv[d], p);
                p = fmaf((float)k1[d], qv[8 + d], p);
            }
            p += __shfl_xor(p, 1);   // combine the two halves of this head

            float a = __expf(fminf(fmaxf(p, -10.0f), 10.0f));
            norm += a;

#pragma unroll
            for (int d = 0; d < 8; ++d) {
                acc[d]     = fmaf((float)v0[d], a, acc[d]);
                acc[8 + d] = fmaf((float)v1[d], a, acc[8 + d]);
            }
        }
    }

    // reduce over the 8 edge-slot lanes (all lanes active here)
#pragma unroll
    for (int m = 8; m <= 32; m <<= 1) {
        norm += __shfl_xor(norm, m, 64);
#pragma unroll
        for (int j = 0; j < 16; ++j) acc[j] += __shfl_xor(acc[j], m, 64);
    }

    if (el == 0) {
        const float inv = 1.0f / (norm + 1e-8f);
        float4* op = (float4*)(out + (size_t)n * 128 + h * 32 + s * 16);
#pragma unroll
        for (int j = 0; j < 4; ++j)
            op[j] = make_float4(acc[4 * j] * inv, acc[4 * j + 1] * inv,
                                acc[4 * j + 2] * inv, acc[4 * j + 3] * inv);
    }
}

// ---------------------------------------------------------------------------
extern "C" void kernel_launch(void* const* d_in, const int* in_sizes, int n_in,
                              void* d_out, int out_size, void* d_ws, size_t ws_size,
                              hipStream_t stream) {
    const float* embeds = (const float*)d_in[0];
    const float* qW     = (const float*)d_in[1];
    const float* kW     = (const float*)d_in[2];
    const float* vW     = (const float*)d_in[3];
    const int*   rows   = (const int*)d_in[4];
    const int*   cols   = (const int*)d_in[5];
    float* out = (float*)d_out;

    // workspace: Q [N*128 f32] | KV2 [N*256 u16] | cnt[N] | slots[N*96] |
    //            Whi[3*16384] | Wlo[3*16384]
    float* Q = (float*)d_ws;
    unsigned short* KV2 = (unsigned short*)(Q + (size_t)N_NODES * LATDIM);
    int* cnt   = (int*)(KV2 + (size_t)N_NODES * 256);
    int* slots = cnt + N_NODES;
    short* Whi = (short*)(slots + (size_t)N_NODES * SLOT_CAP);
    short* Wlo = Whi + 3 * 16384;

    init_kernel<<<192 + (N_NODES + 255) / 256, 256, 0, stream>>>(
        qW, kW, vW, Whi, Wlo, cnt);

    gemm_scatter_kernel<<<TOTAL_BLOCKS, 256, 0, stream>>>(
        embeds, Whi, Wlo, rows, cols, cnt, slots, Q, KV2);

    fused_kernel<<<(N_NODES + 3) / 4, 256, 0, stream>>>(
        Q, KV2, cnt, slots, out);
}

// Round 7
// 185.807 us; speedup vs baseline: 1.9316x; 1.0407x over previous
//
#include <hip/hip_runtime.h>
#include <hip/hip_bf16.h>

#define N_NODES 50000
#define N_EDGES 800000
#define LATDIM 128
#define HEAD 4
#define SLOT_CAP 96

// binned-scatter geometry
#define BUCKETS 196          // ceil(50000/256) buckets of 256 dst nodes
#define BCAP 4608            // records per bucket region (mean 4082, std ~64)
#define A_BLOCKS 98          // phase-A blocks, 8192 edges each
#define A_CHUNKS 2048        // int4 chunks per phase-A block

typedef __attribute__((ext_vector_type(8))) short short8;
typedef __attribute__((ext_vector_type(8))) _Float16 half8;
typedef __attribute__((ext_vector_type(4))) float floatx4;

// ---------------------------------------------------------------------------
// fp32 -> bf16 helpers (RNE via bit math; inputs are finite)
// ---------------------------------------------------------------------------
__device__ __forceinline__ unsigned bf16_rne_bits(float x) {
    unsigned u = __builtin_bit_cast(unsigned, x);
    return (u + 0x7fffu + ((u >> 16) & 1u)) & 0xffff0000u;
}
__device__ __forceinline__ void split_bf16(float x, short& hi, short& lo) {
    unsigned hb = bf16_rne_bits(x);
    hi = (short)(hb >> 16);
    float hf = __builtin_bit_cast(float, hb);
    unsigned lb = bf16_rne_bits(x - hf);
    lo = (short)(lb >> 16);
}

// ---------------------------------------------------------------------------
// init kernel:
//   blocks [0,192): pack fp32 W -> B-fragment-order hi/lo bf16 (Whi/Wlo).
//   blocks [192,192+98): phase-A edge binning. Per block: LDS histogram of
//     its 8192 edges over 196 dst-buckets (ds-atomics), ONE global atomicAdd
//     per (block,bucket) to claim a contiguous chunk of the bucket region
//     (19k global atomics total vs 800k in the old slotted scatter), then
//     records (r&255)<<16 | c written into the private chunk (coalescible).
// ---------------------------------------------------------------------------
__global__ __launch_bounds__(256) void init_kernel(
    const float* __restrict__ qW, const float* __restrict__ kW,
    const float* __restrict__ vW,
    short* __restrict__ Whi, short* __restrict__ Wlo,
    const int* __restrict__ rows, const int* __restrict__ cols,
    int* __restrict__ alloc, unsigned* __restrict__ binned)
{
    const int b = blockIdx.x;
    if (b < 192) {
        const int which = b >> 6;
        const float* W = (which == 0) ? qW : (which == 1) ? kW : vW;
        const int t = (b & 63) * 256 + threadIdx.x;   // [0, 16384)
        const int k = t >> 7, n = t & 127;
        const int c = k >> 5, q = (k >> 3) & 3, j = k & 7;
        short hi, lo;
        split_bf16(W[k * 128 + n], hi, lo);
        const int dst = which * 16384 + ((c * 128 + n) * 4 + q) * 8 + j;
        Whi[dst] = hi;
        Wlo[dst] = lo;
        return;
    }

    // ---- phase A: bin edges by dst>>8 ----
    __shared__ int hist[BUCKETS];
    __shared__ int base[BUCKETS];
    const int ab = b - 192;

    for (int t = threadIdx.x; t < BUCKETS; t += 256) hist[t] = 0;
    __syncthreads();

    // pass 1: histogram (LDS atomics)
#pragma unroll 1
    for (int it = 0; it < 8; ++it) {
        const int ch = ab * A_CHUNKS + it * 256 + threadIdx.x;
        if (ch < N_EDGES / 4) {
            int4 r = ((const int4*)rows)[ch];
            atomicAdd(&hist[r.x >> 8], 1);
            atomicAdd(&hist[r.y >> 8], 1);
            atomicAdd(&hist[r.z >> 8], 1);
            atomicAdd(&hist[r.w >> 8], 1);
        }
    }
    __syncthreads();

    // claim contiguous chunks (one global atomic per bucket per block)
    for (int t = threadIdx.x; t < BUCKETS; t += 256) {
        base[t] = atomicAdd(&alloc[t], hist[t]);
        hist[t] = 0;
    }
    __syncthreads();

    // pass 2: place records into the private chunk
#pragma unroll 1
    for (int it = 0; it < 8; ++it) {
        const int ch = ab * A_CHUNKS + it * 256 + threadIdx.x;
        if (ch < N_EDGES / 4) {
            int4 r = ((const int4*)rows)[ch];
            int4 c = ((const int4*)cols)[ch];
            int bk, p;
            bk = r.x >> 8; p = base[bk] + atomicAdd(&hist[bk], 1);
            if (p < BCAP) binned[(size_t)bk * BCAP + p] =
                ((unsigned)(r.x & 255) << 16) | (unsigned)c.x;
            bk = r.y >> 8; p = base[bk] + atomicAdd(&hist[bk], 1);
            if (p < BCAP) binned[(size_t)bk * BCAP + p] =
                ((unsigned)(r.y & 255) << 16) | (unsigned)c.y;
            bk = r.z >> 8; p = base[bk] + atomicAdd(&hist[bk], 1);
            if (p < BCAP) binned[(size_t)bk * BCAP + p] =
                ((unsigned)(r.z & 255) << 16) | (unsigned)c.z;
            bk = r.w >> 8; p = base[bk] + atomicAdd(&hist[bk], 1);
            if (p < BCAP) binned[(size_t)bk * BCAP + p] =
                ((unsigned)(r.w & 255) << 16) | (unsigned)c.w;
        }
    }
}

// ---------------------------------------------------------------------------
// Kernel 2: phase-B placement + gemm.
//   blocks [0,196): phase B — one bucket per block. cnt privatized to 256
//     LDS counters (ds-atomics, ZERO global atomics); slot writes confined
//     to the bucket's 98 KB window (L2-resident, lines absorb multi-writes);
//     cnt written back coalesced (no global memset needed).
//   blocks >= 196: gemm, byte-identical to round 6 (32-row A-tile, packed-B
//     16-B vector loads, staged coalesced f16-KV2 / f32-Q epilogue).
// KV2[n][h*64+d] = K[n][h*32+d]; KV2[n][h*64+32+d] = V[n][h*32+d]  (f16)
// ---------------------------------------------------------------------------
#define GEMM_TILES ((N_NODES + 31) / 32)              // 1563
#define TOTAL_BLOCKS (BUCKETS + GEMM_TILES)           // 1759
#define LDSP 136   // shorts per LDS row (128 + 8 pad)

__global__ __launch_bounds__(256) void gemm_place_kernel(
    const float* __restrict__ E,
    const short* __restrict__ Whi, const short* __restrict__ Wlo,
    const int* __restrict__ alloc, const unsigned* __restrict__ binned,
    int* __restrict__ cnt, int* __restrict__ slots,
    float* __restrict__ Q, unsigned short* __restrict__ KV2)
{
    __shared__ short AhL[32 * LDSP];
    __shared__ short AlL[32 * LDSP];
    __shared__ unsigned short Stage[32 * 256];   // 16 KB; reused f16 KV / f32 Q
    __shared__ int cl[256];

    const int b = blockIdx.x;

    if (b < BUCKETS) {
        // ---- phase B: LDS-atomic slot placement for bucket b ----
        cl[threadIdx.x] = 0;
        __syncthreads();
        const int nrec = min(alloc[b], BCAP);
        const unsigned* rec = binned + (size_t)b * BCAP;
        for (int i = threadIdx.x; i < nrec; i += 256) {
            const unsigned rc = rec[i];
            const int rl = rc >> 16;
            const int p = atomicAdd(&cl[rl], 1);
            if (p < SLOT_CAP)
                slots[(size_t)(b * 256 + rl) * SLOT_CAP + p] = (int)(rc & 0xffffu);
        }
        __syncthreads();
        const int node = b * 256 + threadIdx.x;
        if (node < N_NODES) cnt[node] = cl[threadIdx.x];
        return;
    }

    // ---- gemm part ----
    const int tile = b - BUCKETS;
    const int r_base = tile * 32;

    // stage + convert A: 32 rows x 32 float4 = 1024 chunks, 4 per thread
#pragma unroll 4
    for (int chnk = threadIdx.x; chnk < 1024; chnk += 256) {
        const int row = chnk >> 5, c4 = chnk & 31;
        int grow = r_base + row;
        if (grow > N_NODES - 1) grow = N_NODES - 1;
        float4 x = ((const float4*)E)[(size_t)grow * 32 + c4];
        short h0, l0, h1, l1, h2, l2, h3, l3;
        split_bf16(x.x, h0, l0);
        split_bf16(x.y, h1, l1);
        split_bf16(x.z, h2, l2);
        split_bf16(x.w, h3, l3);
        *(short4*)(AhL + row * LDSP + c4 * 4) = make_short4(h0, h1, h2, h3);
        *(short4*)(AlL + row * LDSP + c4 * 4) = make_short4(l0, l1, l2, l3);
    }
    __syncthreads();

    const int wave = threadIdx.x >> 6;       // 0..3 -> 32-col stripe
    const int lane = threadIdx.x & 63;
    const int n_base = wave * 32;
    const int ln = lane & 15;
    const int q  = lane >> 4;

    // ---- K and V into Stage (f16, exact global layout) ----
#pragma unroll 1
    for (int which = 1; which < 3; ++which) {
        const int vs = (which == 2) ? 32 : 0;
#pragma unroll 1
        for (int tIdx = 0; tIdx < 2; ++tIdx) {
            short8 Bh[4], Bl[4];
#pragma unroll
            for (int c = 0; c < 4; ++c) {
                const int off = which * 16384 +
                                ((c * 128 + n_base + tIdx * 16 + ln) * 4 + q) * 8;
                Bh[c] = *(const short8*)(Whi + off);
                Bl[c] = *(const short8*)(Wlo + off);
            }

#pragma unroll
            for (int rt = 0; rt < 2; ++rt) {
                const short* ah = AhL + (rt * 16 + ln) * LDSP + q * 8;
                const short* al = AlL + (rt * 16 + ln) * LDSP + q * 8;
                floatx4 acc = {0.f, 0.f, 0.f, 0.f};
#pragma unroll
                for (int c = 0; c < 4; ++c) {
                    short8 Ah = *(const short8*)(ah + c * 32);
                    short8 Al = *(const short8*)(al + c * 32);
                    acc = __builtin_amdgcn_mfma_f32_16x16x32_bf16(Ah, Bh[c], acc, 0, 0, 0);
                    acc = __builtin_amdgcn_mfma_f32_16x16x32_bf16(Ah, Bl[c], acc, 0, 0, 0);
                    acc = __builtin_amdgcn_mfma_f32_16x16x32_bf16(Al, Bh[c], acc, 0, 0, 0);
                }
#pragma unroll
                for (int r = 0; r < 4; ++r) {
                    const int lr = rt * 16 + q * 4 + r;     // local row 0..31
                    Stage[lr * 256 + wave * 64 + tIdx * 16 + ln + vs] =
                        __builtin_bit_cast(unsigned short, (_Float16)acc[r]);
                }
            }
        }
    }
    __syncthreads();

    // ---- coalesced KV2 stream-out: 16 KB contiguous (guard N boundary) ----
#pragma unroll
    for (int it = 0; it < 4; ++it) {
        const int ch = threadIdx.x + it * 256;      // 16-B chunk index
        const int lr = ch >> 5;                      // 512 B per row
        if (r_base + lr < N_NODES)
            ((uint4*)(KV2 + (size_t)r_base * 256))[ch] = ((const uint4*)Stage)[ch];
    }
    __syncthreads();

    // ---- Q into Stage (f32, exact global layout), then stream-out ----
    {
        const int which = 0;
        float* QS = (float*)Stage;
#pragma unroll 1
        for (int tIdx = 0; tIdx < 2; ++tIdx) {
            short8 Bh[4], Bl[4];
#pragma unroll
            for (int c = 0; c < 4; ++c) {
                const int off = which * 16384 +
                                ((c * 128 + n_base + tIdx * 16 + ln) * 4 + q) * 8;
                Bh[c] = *(const short8*)(Whi + off);
                Bl[c] = *(const short8*)(Wlo + off);
            }
            const int cc = n_base + tIdx * 16 + ln;

#pragma unroll
            for (int rt = 0; rt < 2; ++rt) {
                const short* ah = AhL + (rt * 16 + ln) * LDSP + q * 8;
                const short* al = AlL + (rt * 16 + ln) * LDSP + q * 8;
                floatx4 acc = {0.f, 0.f, 0.f, 0.f};
#pragma unroll
                for (int c = 0; c < 4; ++c) {
                    short8 Ah = *(const short8*)(ah + c * 32);
                    short8 Al = *(const short8*)(al + c * 32);
                    acc = __builtin_amdgcn_mfma_f32_16x16x32_bf16(Ah, Bh[c], acc, 0, 0, 0);
                    acc = __builtin_amdgcn_mfma_f32_16x16x32_bf16(Ah, Bl[c], acc, 0, 0, 0);
                    acc = __builtin_amdgcn_mfma_f32_16x16x32_bf16(Al, Bh[c], acc, 0, 0, 0);
                }
#pragma unroll
                for (int r = 0; r < 4; ++r) {
                    const int lr = rt * 16 + q * 4 + r;
                    QS[lr * 128 + cc] = acc[r];
                }
            }
        }
    }
    __syncthreads();

#pragma unroll
    for (int it = 0; it < 4; ++it) {
        const int ch = threadIdx.x + it * 256;      // 16-B chunk index
        const int lr = ch >> 5;                      // 512 B per row
        if (r_base + lr < N_NODES)
            ((float4*)(Q + (size_t)r_base * 128))[ch] = ((const float4*)Stage)[ch];
    }
}

// ---------------------------------------------------------------------------
// L3 fused: one wave per node; lane = (el, h, s). K/V f16 -> v_fma_mix FMAs,
// __expf. Dot = in-lane 16-dim partial + shfl_xor(1); epilogue butterfly.
// ---------------------------------------------------------------------------
__global__ __launch_bounds__(256) void fused_kernel(
    const float* __restrict__ Q,
    const unsigned short* __restrict__ KV2,
    const int* __restrict__ cnt,
    const int* __restrict__ slots,
    float* __restrict__ out)
{
    const int n = blockIdx.x * 4 + (threadIdx.x >> 6);
    if (n >= N_NODES) return;
    const int lane = threadIdx.x & 63;
    const int s  = lane & 1;
    const int h  = (lane >> 1) & 3;
    const int el = lane >> 3;

    int deg = cnt[n];
    if (deg > SLOT_CAP) deg = SLOT_CAP;

    float qv[16];
    {
        const float4* qp = (const float4*)(Q + (size_t)n * 128 + h * 32 + s * 16);
#pragma unroll
        for (int j = 0; j < 4; ++j) {
            float4 t = qp[j];
            qv[4 * j + 0] = t.x; qv[4 * j + 1] = t.y;
            qv[4 * j + 2] = t.z; qv[4 * j + 3] = t.w;
        }
    }

    float acc[16];
#pragma unroll
    for (int j = 0; j < 16; ++j) acc[j] = 0.f;
    float norm = 0.f;

    const int* srow = slots + (size_t)n * SLOT_CAP;

    for (int i = 0; i < deg; i += 8) {
        const int e = i + el;
        if (e < deg) {
            const int col = srow[e];
            const _Float16* kp = (const _Float16*)(KV2 + (size_t)col * 256 + h * 64 + s * 16);
            half8 k0 = *(const half8*)(kp);
            half8 k1 = *(const half8*)(kp + 8);
            half8 v0 = *(const half8*)(kp + 32);
            half8 v1 = *(const half8*)(kp + 40);

            float p = 0.f;
#pragma unroll
            for (int d = 0; d < 8; ++d) {
                p = fmaf((float)k0[d], qv[d], p);
                p = fmaf((float)k1[d], qv[8 + d], p);
            }
            p += __shfl_xor(p, 1);   // combine the two halves of this head

            float a = __expf(fminf(fmaxf(p, -10.0f), 10.0f));
            norm += a;

#pragma unroll
            for (int d = 0; d < 8; ++d) {
                acc[d]     = fmaf((float)v0[d], a, acc[d]);
                acc[8 + d] = fmaf((float)v1[d], a, acc[8 + d]);
            }
        }
    }

    // reduce over the 8 edge-slot lanes (all lanes active here)
#pragma unroll
    for (int m = 8; m <= 32; m <<= 1) {
        norm += __shfl_xor(norm, m, 64);
#pragma unroll
        for (int j = 0; j < 16; ++j) acc[j] += __shfl_xor(acc[j], m, 64);
    }

    if (el == 0) {
        const float inv = 1.0f / (norm + 1e-8f);
        float4* op = (float4*)(out + (size_t)n * 128 + h * 32 + s * 16);
#pragma unroll
        for (int j = 0; j < 4; ++j)
            op[j] = make_float4(acc[4 * j] * inv, acc[4 * j + 1] * inv,
                                acc[4 * j + 2] * inv, acc[4 * j + 3] * inv);
    }
}

// ---------------------------------------------------------------------------
extern "C" void kernel_launch(void* const* d_in, const int* in_sizes, int n_in,
                              void* d_out, int out_size, void* d_ws, size_t ws_size,
                              hipStream_t stream) {
    const float* embeds = (const float*)d_in[0];
    const float* qW     = (const float*)d_in[1];
    const float* kW     = (const float*)d_in[2];
    const float* vW     = (const float*)d_in[3];
    const int*   rows   = (const int*)d_in[4];
    const int*   cols   = (const int*)d_in[5];
    float* out = (float*)d_out;

    // workspace: Q [N*128 f32] | KV2 [N*256 u16] | cnt[N] | slots[N*96] |
    //            Whi[3*16384] | Wlo[3*16384] | alloc[196] | binned[196*4608]
    float* Q = (float*)d_ws;
    unsigned short* KV2 = (unsigned short*)(Q + (size_t)N_NODES * LATDIM);
    int* cnt   = (int*)(KV2 + (size_t)N_NODES * 256);
    int* slots = cnt + N_NODES;
    short* Whi = (short*)(slots + (size_t)N_NODES * SLOT_CAP);
    short* Wlo = Whi + 3 * 16384;
    int* alloc = (int*)(Wlo + 3 * 16384);
    unsigned* binned = (unsigned*)(alloc + BUCKETS);

    hipMemsetAsync(alloc, 0, sizeof(int) * BUCKETS, stream);

    init_kernel<<<192 + A_BLOCKS, 256, 0, stream>>>(
        qW, kW, vW, Whi, Wlo, rows, cols, alloc, binned);

    gemm_place_kernel<<<TOTAL_BLOCKS, 256, 0, stream>>>(
        embeds, Whi, Wlo, alloc, binned, cnt, slots, Q, KV2);

    fused_kernel<<<(N_NODES + 3) / 4, 256, 0, stream>>>(
        Q, KV2, cnt, slots, out);
}